// Round 13
// baseline (423.779 us; speedup 1.0000x reference)
//
#include <hip/hip_runtime.h>
#include <hip/hip_bf16.h>
#include <hip/hip_cooperative_groups.h>

namespace cg = cooperative_groups;

#define N_NODES 40000
#define N_EDGES 640000
#define R_REL 4
#define F_IN 128
#define H_DIM 128
#define NBLK 2
#define G_GRAPHS 64
#define N_OUT 10
#define MAXDEG 10
#define NSCAN_BLK ((N_NODES + 255) / 256)   // 157

typedef unsigned short u16;
typedef float f32x4 __attribute__((ext_vector_type(4)));
typedef short bf16x8 __attribute__((ext_vector_type(8)));

__device__ __forceinline__ float relu_f(float x){ return x > 0.f ? x : 0.f; }

__device__ __forceinline__ u16 f2bf(float f){
  union { float f; unsigned int u; } v; v.f = f;
  unsigned int r = v.u + 0x7fffu + ((v.u >> 16) & 1u);
  return (u16)(r >> 16);
}
__device__ __forceinline__ float b2f(u16 u){
  union { unsigned int u; float f; } v; v.u = ((unsigned int)u) << 16; return v.f;
}
__device__ __forceinline__ float blo(unsigned v){ return b2f((u16)v); }
__device__ __forceinline__ float bhi(unsigned v){ return b2f((u16)(v >> 16)); }

__device__ __forceinline__ void gload16(const void* g, void* l){
  __builtin_amdgcn_global_load_lds(
      (const __attribute__((address_space(1))) void*)g,
      (__attribute__((address_space(3))) void*)l, 16, 0, 0);
}

__device__ __forceinline__ void unpk8(uint4 v, float* f){
  f[0] = blo(v.x); f[1] = bhi(v.x);
  f[2] = blo(v.y); f[3] = bhi(v.y);
  f[4] = blo(v.z); f[5] = bhi(v.z);
  f[6] = blo(v.w); f[7] = bhi(v.w);
}

// ======== cooperative setup: cnt -> scans -> csr_fill -> bucket/goff, + weight cvt ========
__global__ __launch_bounds__(256) void k_setup(
    const int* __restrict__ src, const int* __restrict__ dst, const int* __restrict__ et,
    const int* __restrict__ batch,
    const float* __restrict__ W0, const float* __restrict__ rWrel, const float* __restrict__ rWroot,
    const float* __restrict__ mWl, const float* __restrict__ mWr,
    u16* __restrict__ wt0, u16* __restrict__ wtRel, u16* __restrict__ wtRoot,
    u16* __restrict__ wtWl, u16* __restrict__ wtWr,
    int* __restrict__ cnt4, int* __restrict__ deg, int* __restrict__ row_ptr,
    int* __restrict__ bsum, int* __restrict__ bhist, int* __restrict__ bbase,
    int* __restrict__ pbase, int* __restrict__ bcount, int* __restrict__ boff,
    int* __restrict__ rel_off, int* __restrict__ cursor, int* __restrict__ esrc,
    int* __restrict__ perm, int* __restrict__ goff)
{
  cg::grid_group grid = cg::this_grid();
  __shared__ float sw[32][33];
  __shared__ int s[256];
  __shared__ int lh[16];

  int tid = threadIdx.x;
  int bid = blockIdx.x;
  int gtid = bid * 256 + tid;
  int gsz = gridDim.x * 256;

  // ---- phase 0: zero cnt4 ----
  for (int i = gtid; i < N_NODES * R_REL; i += gsz) cnt4[i] = 0;
  grid.sync();

  // ---- phase 1: edge counts + weight conversion (independent work) ----
  for (int e = gtid; e < N_EDGES; e += gsz)
    atomicAdd(&cnt4[dst[e] * R_REL + et[e]], 1);

  for (int b = bid; b < 55 * 16; b += gridDim.x){
    int m = b >> 4, tile = b & 15;
    const float* S; u16* D; int base;
    if (m < 1){ S = W0; D = wt0; base = m; }
    else if (m < 9){ S = rWrel; D = wtRel; base = m - 1; }
    else if (m < 11){ S = rWroot; D = wtRoot; base = m - 9; }
    else if (m < 33){ S = mWl; D = wtWl; base = m - 11; }
    else { S = mWr; D = wtWr; base = m - 33; }
    S += (size_t)base * 16384;
    D += (size_t)base * 16384;
    int tr = (tile >> 2) * 32, tc = (tile & 3) * 32;
    int c = tid & 31, r0 = tid >> 5;
    #pragma unroll
    for (int i = 0; i < 4; ++i){
      int r = r0 + i * 8;
      sw[r][c] = S[(size_t)(tr + r) * 128 + tc + c];
    }
    __syncthreads();
    #pragma unroll
    for (int i = 0; i < 4; ++i){
      int r = r0 + i * 8;
      D[(size_t)(tc + r) * 128 + tr + c] = f2bf(sw[c][r]);
    }
    __syncthreads();
  }
  grid.sync();

  // ---- phase 2: scan_a (block bid handles nodes [bid*256, bid*256+256)) ----
  {
    int i = bid * 256 + tid;
    if (tid < 16) lh[tid] = 0;
    int d = 0;
    if (i < N_NODES){
      int4 c = *(const int4*)(cnt4 + (size_t)i * 4);
      d = c.x + c.y + c.z + c.w;
      deg[i] = d;
    }
    s[tid] = d;
    __syncthreads();
    if (i < N_NODES){
      int dc = d > MAXDEG ? MAXDEG : d;
      atomicAdd(&lh[dc], 1);
    }
    for (int o = 1; o < 256; o <<= 1){
      int t = (tid >= o) ? s[tid - o] : 0;
      __syncthreads();
      s[tid] += t;
      __syncthreads();
    }
    if (i < N_NODES) row_ptr[i] = s[tid] - d;
    if (tid == 255) bsum[bid] = s[255];
    if (tid <= MAXDEG) bhist[bid * (MAXDEG + 1) + tid] = lh[tid];
  }
  grid.sync();

  // ---- phase 3: block-sum scan + bucket scans (block 0) ----
  if (bid == 0){
    __shared__ int cnt_s[MAXDEG + 1];
    __shared__ int off_s[MAXDEG + 1];
    int v = (tid < NSCAN_BLK) ? bsum[tid] : 0;
    s[tid] = v;
    __syncthreads();
    for (int o = 1; o < 256; o <<= 1){
      int t = (tid >= o) ? s[tid - o] : 0;
      __syncthreads();
      s[tid] += t;
      __syncthreads();
    }
    if (tid < NSCAN_BLK) bbase[tid] = s[tid] - v;

    if (tid <= MAXDEG){
      int run = 0;
      for (int b = 0; b < NSCAN_BLK; ++b){
        pbase[b * (MAXDEG + 1) + tid] = run;
        run += bhist[b * (MAXDEG + 1) + tid];
      }
      cnt_s[tid] = run;
      bcount[tid] = run;
    }
    __syncthreads();
    if (tid == 0){
      int acc = 0;
      for (int dd = 0; dd <= MAXDEG; ++dd){ off_s[dd] = acc; boff[dd] = acc; acc += cnt_s[dd]; }
    }
    __syncthreads();
    if (tid <= MAXDEG){
      int base = off_s[tid];
      for (int b = 0; b < NSCAN_BLK; ++b) pbase[b * (MAXDEG + 1) + tid] += base;
    }
  }
  grid.sync();

  // ---- phase 4: scan_c ----
  {
    int i = bid * 256 + tid;
    if (i < N_NODES){
      int base = row_ptr[i] + bbase[bid];
      row_ptr[i] = base;
      int4 c = *(const int4*)(cnt4 + (size_t)i * 4);
      int4 o;
      o.x = base;
      o.y = base + c.x;
      o.z = o.y + c.y;
      o.w = o.z + c.z;
      *(int4*)(rel_off + (size_t)i * 4) = o;
      *(int4*)(cursor + (size_t)i * 4) = o;
    }
    if (i == 0) row_ptr[N_NODES] = N_EDGES;
  }
  grid.sync();

  // ---- phase 5: csr_fill (grid-stride) + bucket fill + graph boundaries ----
  for (int e = gtid; e < N_EDGES; e += gsz){
    int cell = dst[e] * R_REL + et[e];
    int p = atomicAdd(&cursor[cell], 1);
    esrc[p] = src[e];
  }
  {
    if (tid <= MAXDEG) lh[tid] = 0;
    __syncthreads();
    int i = bid * 256 + tid;
    if (i < N_NODES){
      int d = deg[i]; if (d > MAXDEG) d = MAXDEG;
      int lpos = atomicAdd(&lh[d], 1);
      perm[pbase[bid * (MAXDEG + 1) + d] + lpos] = i;

      int b = batch[i];
      int bp = (i == 0) ? -1 : batch[i - 1];
      for (int g = bp + 1; g <= b; ++g) goff[g] = i;
      if (i == N_NODES - 1){
        for (int g = b + 1; g <= G_GRAPHS; ++g) goff[g] = N_NODES;
      }
    }
  }
}

// ---------- RGCN aggregation: lane-group g = relation g, edge list preloaded in regs ----------
__global__ __launch_bounds__(256) void k_rgcn_agg(const u16* __restrict__ hb,
                                                  const int* __restrict__ rel_off,
                                                  const int* __restrict__ row_ptr,
                                                  const int* __restrict__ esrc,
                                                  u16* __restrict__ meanb){
  int node = blockIdx.x * 4 + (threadIdx.x >> 6);
  int lane = threadIdx.x & 63;
  int g = lane >> 4, c = lane & 15;
  int gbase = lane & 48;   // g*16
  int4 ro = *(const int4*)(rel_off + (size_t)node * 4);
  int nend = row_ptr[node + 1];
  int beg_g = (g == 0) ? ro.x : (g == 1) ? ro.y : (g == 2) ? ro.z : ro.w;
  int end_g = (g == 0) ? ro.y : (g == 1) ? ro.z : (g == 2) ? ro.w : nend;
  int cnt = end_g - beg_g;
  int spre = (c < cnt) ? esrc[beg_g + c] : 0;
  int n16 = cnt < 16 ? cnt : 16;
  float acc[8];
  #pragma unroll
  for (int j = 0; j < 8; ++j) acc[j] = 0.f;
  const u16* hc = hb + c * 8;

  int e = 0;
  for (; e + 4 <= n16; e += 4){
    int s0 = __shfl(spre, gbase + e, 64);
    int s1 = __shfl(spre, gbase + e + 1, 64);
    int s2 = __shfl(spre, gbase + e + 2, 64);
    int s3 = __shfl(spre, gbase + e + 3, 64);
    uint4 v0 = *(const uint4*)(hc + (size_t)s0 * H_DIM);
    uint4 v1 = *(const uint4*)(hc + (size_t)s1 * H_DIM);
    uint4 v2 = *(const uint4*)(hc + (size_t)s2 * H_DIM);
    uint4 v3 = *(const uint4*)(hc + (size_t)s3 * H_DIM);
    float f0[8], f1[8], f2[8], f3[8];
    unpk8(v0, f0); unpk8(v1, f1); unpk8(v2, f2); unpk8(v3, f3);
    #pragma unroll
    for (int j = 0; j < 8; ++j) acc[j] += (f0[j] + f1[j]) + (f2[j] + f3[j]);
  }
  for (; e < n16; ++e){
    int s = __shfl(spre, gbase + e, 64);
    uint4 v = *(const uint4*)(hc + (size_t)s * H_DIM);
    float f[8];
    unpk8(v, f);
    #pragma unroll
    for (int j = 0; j < 8; ++j) acc[j] += f[j];
  }
  for (; e < cnt; ++e){            // rare tail (segment > 16 edges)
    int s = esrc[beg_g + e];
    uint4 v = *(const uint4*)(hc + (size_t)s * H_DIM);
    float f[8];
    unpk8(v, f);
    #pragma unroll
    for (int j = 0; j < 8; ++j) acc[j] += f[j];
  }
  float inv = cnt > 0 ? 1.f / (float)cnt : 0.f;
  unsigned p[4];
  #pragma unroll
  for (int q = 0; q < 4; ++q)
    p[q] = (unsigned)f2bf(acc[q * 2] * inv) | ((unsigned)f2bf(acc[q * 2 + 1] * inv) << 16);
  *(uint4*)(meanb + (size_t)node * R_REL * H_DIM + g * H_DIM + c * 8) =
      make_uint4(p[0], p[1], p[2], p[3]);
}

// ---------- MFConv aggregation: 64-edge register preload + 4-slot gather ----------
__global__ __launch_bounds__(256) void k_mf_agg(const u16* __restrict__ hb,
                                                const int* __restrict__ row_ptr,
                                                const int* __restrict__ esrc,
                                                u16* __restrict__ aggb){
  int node = blockIdx.x * 4 + (threadIdx.x >> 6);
  int lane = threadIdx.x & 63;
  int g = lane >> 4, c = lane & 15;
  int beg = row_ptr[node], end = row_ptr[node + 1];
  int T = end - beg;
  int spre = (lane < T) ? esrc[beg + lane] : 0;
  int n64 = T < 64 ? T : 64;
  float acc[8];
  #pragma unroll
  for (int j = 0; j < 8; ++j) acc[j] = 0.f;
  const u16* hc = hb + c * 8;

  int i = 0;
  for (; i + 8 <= n64; i += 8){
    int sA = __shfl(spre, i + g, 64);
    int sB = __shfl(spre, i + 4 + g, 64);
    uint4 vA = *(const uint4*)(hc + (size_t)sA * H_DIM);
    uint4 vB = *(const uint4*)(hc + (size_t)sB * H_DIM);
    float fA[8], fB[8];
    unpk8(vA, fA); unpk8(vB, fB);
    #pragma unroll
    for (int j = 0; j < 8; ++j) acc[j] += fA[j] + fB[j];
  }
  for (; i < n64; i += 4){
    int e = i + g;
    int ce = e < n64 ? e : n64 - 1;
    int s = __shfl(spre, ce, 64);
    uint4 v = *(const uint4*)(hc + (size_t)s * H_DIM);
    float f[8];
    unpk8(v, f);
    float m = (e < n64) ? 1.f : 0.f;
    #pragma unroll
    for (int j = 0; j < 8; ++j) acc[j] += f[j] * m;
  }
  for (int e2 = 64 + g; e2 < T; e2 += 4){   // astronomically rare tail (deg > 64)
    int s = esrc[beg + e2];
    uint4 v = *(const uint4*)(hc + (size_t)s * H_DIM);
    float f[8];
    unpk8(v, f);
    #pragma unroll
    for (int j = 0; j < 8; ++j) acc[j] += f[j];
  }
  #pragma unroll
  for (int j = 0; j < 8; ++j){
    acc[j] += __shfl_xor(acc[j], 16, 64);
    acc[j] += __shfl_xor(acc[j], 32, 64);
  }
  if (g == 0){
    unsigned p[4];
    #pragma unroll
    for (int q = 0; q < 4; ++q)
      p[q] = (unsigned)f2bf(acc[q * 2]) | ((unsigned)f2bf(acc[q * 2 + 1]) << 16);
    uint4 P = make_uint4(p[0], p[1], p[2], p[3]);
    *(uint4*)(aggb + (size_t)node * H_DIM + c * 8) = P;
  }
}

// ======== LDS-staged MFMA GEMMs ========

// ---------- gemm0: fp32 x loaded+converted in-kernel ----------
__global__ __launch_bounds__(512) void k_gemm0(const float* __restrict__ x, const u16* __restrict__ wt,
                                               const float* __restrict__ bias, u16* __restrict__ hbo){
  __shared__ u16 lds[32][128];
  int tid = threadIdx.x;
  int w = tid >> 6, lane = tid & 63;
  int m0 = blockIdx.x * 32;
  {
    int rg = lane >> 4, cb = (lane & 15) << 4;
    int srow = w * 4 + rg;
    int swcb = cb ^ ((srow & 7) << 4);
    const float* xs = x + (size_t)(m0 + srow) * F_IN + (swcb >> 1);
    float4 u = *(const float4*)xs;
    float4 v = *(const float4*)(xs + 4);
    unsigned p0 = (unsigned)f2bf(u.x) | ((unsigned)f2bf(u.y) << 16);
    unsigned p1 = (unsigned)f2bf(u.z) | ((unsigned)f2bf(u.w) << 16);
    unsigned p2 = (unsigned)f2bf(v.x) | ((unsigned)f2bf(v.y) << 16);
    unsigned p3 = (unsigned)f2bf(v.z) | ((unsigned)f2bf(v.w) << 16);
    *(uint4*)((char*)&lds[0][0] + w * 1024 + lane * 16) = make_uint4(p0, p1, p2, p3);
  }
  __syncthreads();

  int arow = lane & 15, kg = lane >> 4;
  int col = w * 16 + arow;
  f32x4 acc[2];
  acc[0] = (f32x4){0.f, 0.f, 0.f, 0.f};
  acc[1] = (f32x4){0.f, 0.f, 0.f, 0.f};
  bf16x8 b[4];
  #pragma unroll
  for (int kk = 0; kk < 4; ++kk)
    b[kk] = *(const bf16x8*)(wt + (size_t)col * F_IN + kk * 32 + kg * 8);
  #pragma unroll
  for (int rt = 0; rt < 2; ++rt){
    int row = rt * 16 + arow;
    const char* base = (const char*)&lds[0][0] + row * 256;
    int sx = (row & 7) << 4;
    #pragma unroll
    for (int kk = 0; kk < 4; ++kk){
      bf16x8 a = *(const bf16x8*)(base + ((kk * 64 + kg * 16) ^ sx));
      acc[rt] = __builtin_amdgcn_mfma_f32_16x16x32_bf16(a, b[kk], acc[rt], 0, 0, 0);
    }
  }
  float bb = bias[col];
  #pragma unroll
  for (int rt = 0; rt < 2; ++rt)
    #pragma unroll
    for (int j = 0; j < 4; ++j){
      int gr = m0 + rt * 16 + kg * 4 + j;
      hbo[(size_t)gr * H_DIM + col] = f2bf(relu_f(acc[rt][j] + bb));
    }
}

__global__ __launch_bounds__(512) void k_rgcn_gemm(const u16* __restrict__ meanb, const u16* __restrict__ hb,
                                                   const u16* __restrict__ wrel, const u16* __restrict__ wroot,
                                                   const float* __restrict__ bias, u16* __restrict__ hbo){
  __shared__ u16 lds[5][32][128];   // 40 KB
  int tid = threadIdx.x;
  int w = tid >> 6, lane = tid & 63;
  int m0 = blockIdx.x * 32;
  int rg = lane >> 4, cb = (lane & 15) << 4;
  int srow = w * 4 + rg;
  int swcb = cb ^ ((srow & 7) << 4);
  #pragma unroll
  for (int s = 0; s < 4; ++s)
    gload16(meanb + ((size_t)(m0 + srow) * R_REL + s) * H_DIM + (swcb >> 1), &lds[s][w * 4][0]);
  gload16(hb + (size_t)(m0 + srow) * H_DIM + (swcb >> 1), &lds[4][w * 4][0]);
  __syncthreads();

  int arow = lane & 15, kg = lane >> 4;
  int col = w * 16 + arow;
  f32x4 acc[2];
  acc[0] = (f32x4){0.f, 0.f, 0.f, 0.f};
  acc[1] = (f32x4){0.f, 0.f, 0.f, 0.f};
  #pragma unroll
  for (int s = 0; s < 5; ++s){
    const u16* WT = (s < 4) ? wrel + (size_t)s * 16384 : wroot;
    bf16x8 b[4];
    #pragma unroll
    for (int kk = 0; kk < 4; ++kk)
      b[kk] = *(const bf16x8*)(WT + (size_t)col * H_DIM + kk * 32 + kg * 8);
    #pragma unroll
    for (int rt = 0; rt < 2; ++rt){
      int row = rt * 16 + arow;
      const char* base = (const char*)&lds[s][0][0] + row * 256;
      int sx = (row & 7) << 4;
      #pragma unroll
      for (int kk = 0; kk < 4; ++kk){
        bf16x8 a = *(const bf16x8*)(base + ((kk * 64 + kg * 16) ^ sx));
        acc[rt] = __builtin_amdgcn_mfma_f32_16x16x32_bf16(a, b[kk], acc[rt], 0, 0, 0);
      }
    }
  }
  float bb = bias[col];
  #pragma unroll
  for (int rt = 0; rt < 2; ++rt)
    #pragma unroll
    for (int j = 0; j < 4; ++j){
      int gr = m0 + rt * 16 + kg * 4 + j;
      hbo[(size_t)gr * H_DIM + col] = f2bf(relu_f(acc[rt][j] + bb));
    }
}

template<int FINAL>
__global__ __launch_bounds__(512) void k_mf_gemm(const u16* __restrict__ aggb, const u16* __restrict__ hb,
                                                 const u16* __restrict__ wl, const u16* __restrict__ wr,
                                                 const float* __restrict__ bl,
                                                 const int* __restrict__ bcount, const int* __restrict__ boff,
                                                 const int* __restrict__ perm,
                                                 u16* __restrict__ hbo, float* __restrict__ hf){
  __shared__ u16 lds[2][32][128];   // 16 KB
  __shared__ int rows_s[32];
  int t = blockIdx.x;
  int d = -1, tile = 0;
  for (int dd = 0; dd <= MAXDEG; ++dd){
    int nt = (bcount[dd] + 31) >> 5;
    if (t < nt){ d = dd; tile = t; break; }
    t -= nt;
  }
  if (d < 0) return;
  int cnt_d = bcount[d];
  int start = boff[d] + tile * 32;
  int nrows = cnt_d - tile * 32; if (nrows > 32) nrows = 32;

  int tid = threadIdx.x;
  int w = tid >> 6, lane = tid & 63;
  if (tid < 32) rows_s[tid] = (tid < nrows) ? perm[start + tid] : -1;

  int rg = lane >> 4, cb = (lane & 15) << 4;
  int srow = w * 4 + rg;
  int swcb = cb ^ ((srow & 7) << 4);
  int node = perm[start + (srow < nrows ? srow : 0)];
  gload16(aggb + (size_t)node * H_DIM + (swcb >> 1), &lds[0][w * 4][0]);
  gload16(hb   + (size_t)node * H_DIM + (swcb >> 1), &lds[1][w * 4][0]);
  __syncthreads();

  int arow = lane & 15, kg = lane >> 4;
  int col = w * 16 + arow;
  f32x4 acc[2];
  acc[0] = (f32x4){0.f, 0.f, 0.f, 0.f};
  acc[1] = (f32x4){0.f, 0.f, 0.f, 0.f};
  #pragma unroll
  for (int s = 0; s < 2; ++s){
    const u16* WT = (s ? wr : wl) + (size_t)d * 16384;
    bf16x8 b[4];
    #pragma unroll
    for (int kk = 0; kk < 4; ++kk)
      b[kk] = *(const bf16x8*)(WT + (size_t)col * H_DIM + kk * 32 + kg * 8);
    #pragma unroll
    for (int rt = 0; rt < 2; ++rt){
      int row = rt * 16 + arow;
      const char* base = (const char*)&lds[s][0][0] + row * 256;
      int sx = (row & 7) << 4;
      #pragma unroll
      for (int kk = 0; kk < 4; ++kk){
        bf16x8 a = *(const bf16x8*)(base + ((kk * 64 + kg * 16) ^ sx));
        acc[rt] = __builtin_amdgcn_mfma_f32_16x16x32_bf16(a, b[kk], acc[rt], 0, 0, 0);
      }
    }
  }
  float bb = bl[(size_t)d * H_DIM + col];
  #pragma unroll
  for (int rt = 0; rt < 2; ++rt)
    #pragma unroll
    for (int j = 0; j < 4; ++j){
      int gr = rows_s[rt * 16 + kg * 4 + j];
      if (gr >= 0){
        float v = acc[rt][j] + bb;
        if (FINAL) hf[(size_t)gr * H_DIM + col] = v;
        else       hbo[(size_t)gr * H_DIM + col] = f2bf(relu_f(v));
      }
    }
}

// ---------- merged pooling + MLP ----------
__global__ __launch_bounds__(256) void k_poolmlp(const float* __restrict__ h, const int* __restrict__ goff,
                                                 const float* __restrict__ W1, const float* __restrict__ b1,
                                                 const float* __restrict__ W2, const float* __restrict__ b2,
                                                 float* __restrict__ out){
  __shared__ float4 sred[8][32];
  __shared__ float pv[128];
  __shared__ float Ts[128];
  int g = blockIdx.x;
  int tid = threadIdx.x;
  int rg = tid >> 5, lane = tid & 31;
  int beg = goff[g], end = goff[g + 1];
  float4 acc = make_float4(0.f, 0.f, 0.f, 0.f);
  for (int n = beg + rg; n < end; n += 8){
    float4 v = ((const float4*)(h + (size_t)n * H_DIM))[lane];
    acc.x += v.x; acc.y += v.y; acc.z += v.z; acc.w += v.w;
  }
  sred[rg][lane] = acc;
  __syncthreads();
  if (tid < 32){
    float4 s = sred[0][tid];
    #pragma unroll
    for (int r = 1; r < 8; ++r){
      float4 v = sred[r][tid];
      s.x += v.x; s.y += v.y; s.z += v.z; s.w += v.w;
    }
    *(float4*)&pv[tid * 4] = s;
  }
  __syncthreads();
  if (tid < 128){
    float s = b1[tid];
    for (int k = 0; k < H_DIM; ++k) s += pv[k] * W1[k * H_DIM + tid];
    Ts[tid] = relu_f(s);
  }
  __syncthreads();
  if (tid < N_OUT){
    float o = b2[tid];
    for (int k = 0; k < H_DIM; ++k) o += Ts[k] * W2[k * N_OUT + tid];
    out[(size_t)g * N_OUT + tid] = o;
  }
}

extern "C" void kernel_launch(void* const* d_in, const int* in_sizes, int n_in,
                              void* d_out, int out_size, void* d_ws, size_t ws_size,
                              hipStream_t stream){
  const float* x      = (const float*)d_in[0];
  const int*   ei     = (const int*)d_in[1];
  const int*   ea     = (const int*)d_in[2];
  const int*   batch  = (const int*)d_in[3];
  const float* W0     = (const float*)d_in[4];
  const float* b0     = (const float*)d_in[5];
  const float* rWrel  = (const float*)d_in[6];
  const float* rWroot = (const float*)d_in[7];
  const float* rb     = (const float*)d_in[8];
  const float* mWl    = (const float*)d_in[9];
  const float* mbl    = (const float*)d_in[10];
  const float* mWr    = (const float*)d_in[11];
  const float* W1     = (const float*)d_in[12];
  const float* b1     = (const float*)d_in[13];
  const float* W2     = (const float*)d_in[14];
  const float* b2     = (const float*)d_in[15];
  float* out = (float*)d_out;

  const int* src = ei;
  const int* dst = ei + N_EDGES;

  char* ws = (char*)d_ws;
  size_t off = 0;
  auto alloc = [&](size_t bytes) -> void* {
    void* p = ws + off;
    off += (bytes + 255) & ~(size_t)255;
    return p;
  };
  u16* hbA     = (u16*)alloc((size_t)N_NODES * H_DIM * 2);
  u16* hbB     = (u16*)alloc((size_t)N_NODES * H_DIM * 2);
  u16* meanb   = (u16*)alloc((size_t)N_NODES * R_REL * H_DIM * 2);
  u16* aggb    = meanb;  // reuse
  float* hf    = (float*)alloc((size_t)N_NODES * H_DIM * 4);
  u16* wt0     = (u16*)alloc((size_t)1 * 16384 * 2);
  u16* wtRel   = (u16*)alloc((size_t)NBLK * R_REL * 16384 * 2);
  u16* wtRoot  = (u16*)alloc((size_t)NBLK * 16384 * 2);
  u16* wtWl    = (u16*)alloc((size_t)NBLK * (MAXDEG + 1) * 16384 * 2);
  u16* wtWr    = (u16*)alloc((size_t)NBLK * (MAXDEG + 1) * 16384 * 2);
  int* cnt4     = (int*)alloc((size_t)N_NODES * R_REL * 4);
  int* deg      = (int*)alloc((size_t)N_NODES * 4);
  int* row_ptr  = (int*)alloc((size_t)(N_NODES + 1) * 4);
  int* rel_off  = (int*)alloc((size_t)N_NODES * R_REL * 4);
  int* cursor   = (int*)alloc((size_t)N_NODES * R_REL * 4);
  int* esrc     = (int*)alloc((size_t)N_EDGES * 4);
  int* bsum     = (int*)alloc((size_t)NSCAN_BLK * 4);
  int* bbase    = (int*)alloc((size_t)NSCAN_BLK * 4);
  int* bhist    = (int*)alloc((size_t)NSCAN_BLK * (MAXDEG + 1) * 4);
  int* pbase    = (int*)alloc((size_t)NSCAN_BLK * (MAXDEG + 1) * 4);
  int* perm     = (int*)alloc((size_t)N_NODES * 4);
  int* bcount   = (int*)alloc(16 * 4);
  int* boff     = (int*)alloc(16 * 4);
  int* goff     = (int*)alloc((size_t)(G_GRAPHS + 1) * 4);

  // ---- cooperative setup (replaces memset + 7 kernels) ----
  {
    void* args[] = {
      (void*)&src, (void*)&dst, (void*)&ea, (void*)&batch,
      (void*)&W0, (void*)&rWrel, (void*)&rWroot, (void*)&mWl, (void*)&mWr,
      (void*)&wt0, (void*)&wtRel, (void*)&wtRoot, (void*)&wtWl, (void*)&wtWr,
      (void*)&cnt4, (void*)&deg, (void*)&row_ptr, (void*)&bsum, (void*)&bhist,
      (void*)&bbase, (void*)&pbase, (void*)&bcount, (void*)&boff,
      (void*)&rel_off, (void*)&cursor, (void*)&esrc, (void*)&perm, (void*)&goff
    };
    hipLaunchCooperativeKernel((void*)k_setup, dim3(NSCAN_BLK), dim3(256), args, 0, stream);
  }

  k_gemm0<<<N_NODES / 32, 512, 0, stream>>>(x, wt0, b0, hbA);

  u16* hin = hbA;
  u16* hout = hbB;
  for (int blk = 0; blk < NBLK; ++blk){
    k_rgcn_agg<<<N_NODES / 4, 256, 0, stream>>>(hin, rel_off, row_ptr, esrc, meanb);
    k_rgcn_gemm<<<N_NODES / 32, 512, 0, stream>>>(meanb, hin,
        wtRel + (size_t)blk * R_REL * 16384,
        wtRoot + (size_t)blk * 16384,
        rb + (size_t)blk * H_DIM, hout);
    { u16* tmp = hin; hin = hout; hout = tmp; }

    k_mf_agg<<<N_NODES / 4, 256, 0, stream>>>(hin, row_ptr, esrc, aggb);
    const u16* wl_b = wtWl + (size_t)blk * (MAXDEG + 1) * 16384;
    const u16* wr_b = wtWr + (size_t)blk * (MAXDEG + 1) * 16384;
    const float* bl_b = mbl + (size_t)blk * (MAXDEG + 1) * H_DIM;
    int grid_mf = N_NODES / 32 + MAXDEG + 1;
    if (blk == NBLK - 1)
      k_mf_gemm<1><<<grid_mf, 512, 0, stream>>>(aggb, hin, wl_b, wr_b, bl_b,
                                                bcount, boff, perm, hout, hf);
    else
      k_mf_gemm<0><<<grid_mf, 512, 0, stream>>>(aggb, hin, wl_b, wr_b, bl_b,
                                                bcount, boff, perm, hout, hf);
    { u16* tmp = hin; hin = hout; hout = tmp; }
  }

  k_poolmlp<<<G_GRAPHS, 256, 0, stream>>>(hf, goff, W1, b1, W2, b2, out);
}

// Round 14
// 340.741 us; speedup vs baseline: 1.2437x; 1.2437x over previous
//
#include <hip/hip_runtime.h>
#include <hip/hip_bf16.h>

#define N_NODES 40000
#define N_EDGES 640000
#define R_REL 4
#define F_IN 128
#define H_DIM 128
#define NBLK 2
#define G_GRAPHS 64
#define N_OUT 10
#define MAXDEG 10
#define NSCAN_BLK ((N_NODES + 255) / 256)   // 157

typedef unsigned short u16;
typedef float f32x4 __attribute__((ext_vector_type(4)));
typedef short bf16x8 __attribute__((ext_vector_type(8)));

__device__ __forceinline__ float relu_f(float x){ return x > 0.f ? x : 0.f; }

__device__ __forceinline__ u16 f2bf(float f){
  union { float f; unsigned int u; } v; v.f = f;
  unsigned int r = v.u + 0x7fffu + ((v.u >> 16) & 1u);
  return (u16)(r >> 16);
}
__device__ __forceinline__ float b2f(u16 u){
  union { unsigned int u; float f; } v; v.u = ((unsigned int)u) << 16; return v.f;
}
__device__ __forceinline__ float blo(unsigned v){ return b2f((u16)v); }
__device__ __forceinline__ float bhi(unsigned v){ return b2f((u16)(v >> 16)); }

__device__ __forceinline__ void gload16(const void* g, void* l){
  __builtin_amdgcn_global_load_lds(
      (const __attribute__((address_space(1))) void*)g,
      (__attribute__((address_space(3))) void*)l, 16, 0, 0);
}

// unpack 16B (8 bf16) to 8 floats
__device__ __forceinline__ void unpk8(uint4 v, float* f){
  f[0] = blo(v.x); f[1] = bhi(v.x);
  f[2] = blo(v.y); f[3] = bhi(v.y);
  f[4] = blo(v.z); f[5] = bhi(v.z);
  f[6] = blo(v.w); f[7] = bhi(v.w);
}

// ---------- per-(node,rel) counts ----------
__global__ void k_cnt(const int* __restrict__ dst, const int* __restrict__ et, int* __restrict__ cnt4){
  int e = blockIdx.x * blockDim.x + threadIdx.x;
  if (e >= N_EDGES) return;
  atomicAdd(&cnt4[dst[e] * R_REL + et[e]], 1);
}

// ---------- scan A ----------
__global__ __launch_bounds__(256) void k_scan_a(const int* __restrict__ cnt4, int* __restrict__ deg,
                                                int* __restrict__ row_ptr, int* __restrict__ bsum,
                                                int* __restrict__ bhist){
  __shared__ int s[256];
  __shared__ int lh[16];
  int tid = threadIdx.x;
  int i = blockIdx.x * 256 + tid;
  if (tid < 16) lh[tid] = 0;
  int d = 0;
  if (i < N_NODES){
    int4 c = *(const int4*)(cnt4 + (size_t)i * 4);
    d = c.x + c.y + c.z + c.w;
    deg[i] = d;
  }
  s[tid] = d;
  __syncthreads();
  if (i < N_NODES){
    int dc = d > MAXDEG ? MAXDEG : d;
    atomicAdd(&lh[dc], 1);
  }
  for (int o = 1; o < 256; o <<= 1){
    int t = (tid >= o) ? s[tid - o] : 0;
    __syncthreads();
    s[tid] += t;
    __syncthreads();
  }
  if (i < N_NODES) row_ptr[i] = s[tid] - d;
  if (tid == 255) bsum[blockIdx.x] = s[255];
  if (tid <= MAXDEG) bhist[blockIdx.x * (MAXDEG + 1) + tid] = lh[tid];
}

// ---------- merged block-sum scan + bucket scans ----------
__global__ __launch_bounds__(256) void k_scan_bb(int* __restrict__ bsum, int* __restrict__ bbase,
                                                 const int* __restrict__ bhist, int* __restrict__ pbase,
                                                 int* __restrict__ bcount, int* __restrict__ boff){
  __shared__ int s[256];
  __shared__ int cnt_s[MAXDEG + 1];
  __shared__ int off_s[MAXDEG + 1];
  int tid = threadIdx.x;
  int v = (tid < NSCAN_BLK) ? bsum[tid] : 0;
  s[tid] = v;
  __syncthreads();
  for (int o = 1; o < 256; o <<= 1){
    int t = (tid >= o) ? s[tid - o] : 0;
    __syncthreads();
    s[tid] += t;
    __syncthreads();
  }
  if (tid < NSCAN_BLK) bbase[tid] = s[tid] - v;

  if (tid <= MAXDEG){
    int run = 0;
    for (int b = 0; b < NSCAN_BLK; ++b){
      pbase[b * (MAXDEG + 1) + tid] = run;
      run += bhist[b * (MAXDEG + 1) + tid];
    }
    cnt_s[tid] = run;
    bcount[tid] = run;
  }
  __syncthreads();
  if (tid == 0){
    int acc = 0;
    for (int dd = 0; dd <= MAXDEG; ++dd){ off_s[dd] = acc; boff[dd] = acc; acc += cnt_s[dd]; }
  }
  __syncthreads();
  if (tid <= MAXDEG){
    int base = off_s[tid];
    for (int b = 0; b < NSCAN_BLK; ++b) pbase[b * (MAXDEG + 1) + tid] += base;
  }
}

// ---------- scan C ----------
__global__ __launch_bounds__(256) void k_scan_c(int* __restrict__ row_ptr, const int* __restrict__ bbase,
                                                const int* __restrict__ cnt4, int* __restrict__ rel_off,
                                                int* __restrict__ cursor){
  int i = blockIdx.x * 256 + threadIdx.x;
  if (i < N_NODES){
    int base = row_ptr[i] + bbase[blockIdx.x];
    row_ptr[i] = base;
    int4 c = *(const int4*)(cnt4 + (size_t)i * 4);
    int4 o;
    o.x = base;
    o.y = base + c.x;
    o.z = o.y + c.y;
    o.w = o.z + c.z;
    *(int4*)(rel_off + (size_t)i * 4) = o;
    *(int4*)(cursor + (size_t)i * 4) = o;
  }
  if (i == 0) row_ptr[N_NODES] = N_EDGES;
}

// ---------- CSR fill ----------
__global__ void k_csr_fill(const int* __restrict__ src, const int* __restrict__ dst,
                           const int* __restrict__ et,
                           int* __restrict__ cursor, int* __restrict__ esrc){
  int e = blockIdx.x * blockDim.x + threadIdx.x;
  if (e >= N_EDGES) return;
  int cell = dst[e] * R_REL + et[e];
  int p = atomicAdd(&cursor[cell], 1);
  esrc[p] = src[e];
}

// ---------- bucket fill + graph boundaries ----------
__global__ __launch_bounds__(256) void k_bfill_goff(const int* __restrict__ deg, const int* __restrict__ pbase,
                                                    int* __restrict__ perm,
                                                    const int* __restrict__ batch, int* __restrict__ goff){
  __shared__ int lh[MAXDEG + 1];
  int tid = threadIdx.x;
  if (tid <= MAXDEG) lh[tid] = 0;
  __syncthreads();
  int i = blockIdx.x * 256 + tid;
  if (i < N_NODES){
    int d = deg[i]; if (d > MAXDEG) d = MAXDEG;
    int lpos = atomicAdd(&lh[d], 1);
    perm[pbase[blockIdx.x * (MAXDEG + 1) + d] + lpos] = i;

    int b = batch[i];
    int bp = (i == 0) ? -1 : batch[i - 1];
    for (int g = bp + 1; g <= b; ++g) goff[g] = i;
    if (i == N_NODES - 1){
      for (int g = b + 1; g <= G_GRAPHS; ++g) goff[g] = N_NODES;
    }
  }
}

// ---------- all weight tensors: fp32 -> bf16 transposed ----------
__global__ __launch_bounds__(256) void k_cvtW_all(const float* __restrict__ s0, const float* __restrict__ s1,
                                                  const float* __restrict__ s2, const float* __restrict__ s3,
                                                  const float* __restrict__ s4,
                                                  u16* __restrict__ d0, u16* __restrict__ d1,
                                                  u16* __restrict__ d2, u16* __restrict__ d3,
                                                  u16* __restrict__ d4){
  __shared__ float s[32][33];
  int b = blockIdx.x;
  int m = b >> 4, tile = b & 15;
  const float* S; u16* D; int base;
  if (m < 1){ S = s0; D = d0; base = m; }
  else if (m < 9){ S = s1; D = d1; base = m - 1; }
  else if (m < 11){ S = s2; D = d2; base = m - 9; }
  else if (m < 33){ S = s3; D = d3; base = m - 11; }
  else { S = s4; D = d4; base = m - 33; }
  S += (size_t)base * 16384;
  D += (size_t)base * 16384;
  int tr = (tile >> 2) * 32, tc = (tile & 3) * 32;
  int c = threadIdx.x & 31, r0 = threadIdx.x >> 5;
  #pragma unroll
  for (int i = 0; i < 4; ++i){
    int r = r0 + i * 8;
    s[r][c] = S[(size_t)(tr + r) * 128 + tc + c];
  }
  __syncthreads();
  #pragma unroll
  for (int i = 0; i < 4; ++i){
    int r = r0 + i * 8;
    D[(size_t)(tc + r) * 128 + tr + c] = f2bf(s[c][r]);
  }
}

// ---------- RGCN aggregation: lane-group g = relation g, edge list preloaded in regs ----------
__global__ __launch_bounds__(256) void k_rgcn_agg(const u16* __restrict__ hb,
                                                  const int* __restrict__ rel_off,
                                                  const int* __restrict__ row_ptr,
                                                  const int* __restrict__ esrc,
                                                  u16* __restrict__ meanb){
  int node = blockIdx.x * 4 + (threadIdx.x >> 6);
  int lane = threadIdx.x & 63;
  int g = lane >> 4, c = lane & 15;
  int gbase = lane & 48;   // g*16
  int4 ro = *(const int4*)(rel_off + (size_t)node * 4);
  int nend = row_ptr[node + 1];
  int beg_g = (g == 0) ? ro.x : (g == 1) ? ro.y : (g == 2) ? ro.z : ro.w;
  int end_g = (g == 0) ? ro.y : (g == 1) ? ro.z : (g == 2) ? ro.w : nend;
  int cnt = end_g - beg_g;
  int spre = (c < cnt) ? esrc[beg_g + c] : 0;
  int n16 = cnt < 16 ? cnt : 16;
  float acc[8];
  #pragma unroll
  for (int j = 0; j < 8; ++j) acc[j] = 0.f;
  const u16* hc = hb + c * 8;

  int e = 0;
  for (; e + 4 <= n16; e += 4){
    int s0 = __shfl(spre, gbase + e, 64);
    int s1 = __shfl(spre, gbase + e + 1, 64);
    int s2 = __shfl(spre, gbase + e + 2, 64);
    int s3 = __shfl(spre, gbase + e + 3, 64);
    uint4 v0 = *(const uint4*)(hc + (size_t)s0 * H_DIM);
    uint4 v1 = *(const uint4*)(hc + (size_t)s1 * H_DIM);
    uint4 v2 = *(const uint4*)(hc + (size_t)s2 * H_DIM);
    uint4 v3 = *(const uint4*)(hc + (size_t)s3 * H_DIM);
    float f0[8], f1[8], f2[8], f3[8];
    unpk8(v0, f0); unpk8(v1, f1); unpk8(v2, f2); unpk8(v3, f3);
    #pragma unroll
    for (int j = 0; j < 8; ++j) acc[j] += (f0[j] + f1[j]) + (f2[j] + f3[j]);
  }
  for (; e < n16; ++e){
    int s = __shfl(spre, gbase + e, 64);
    uint4 v = *(const uint4*)(hc + (size_t)s * H_DIM);
    float f[8];
    unpk8(v, f);
    #pragma unroll
    for (int j = 0; j < 8; ++j) acc[j] += f[j];
  }
  for (; e < cnt; ++e){            // rare tail (segment > 16 edges)
    int s = esrc[beg_g + e];
    uint4 v = *(const uint4*)(hc + (size_t)s * H_DIM);
    float f[8];
    unpk8(v, f);
    #pragma unroll
    for (int j = 0; j < 8; ++j) acc[j] += f[j];
  }
  float inv = cnt > 0 ? 1.f / (float)cnt : 0.f;
  unsigned p[4];
  #pragma unroll
  for (int q = 0; q < 4; ++q)
    p[q] = (unsigned)f2bf(acc[q * 2] * inv) | ((unsigned)f2bf(acc[q * 2 + 1] * inv) << 16);
  *(uint4*)(meanb + (size_t)node * R_REL * H_DIM + g * H_DIM + c * 8) =
      make_uint4(p[0], p[1], p[2], p[3]);
}

// ---------- MFConv aggregation: 64-edge register preload + 4-slot gather ----------
__global__ __launch_bounds__(256) void k_mf_agg(const u16* __restrict__ hb,
                                                const int* __restrict__ row_ptr,
                                                const int* __restrict__ esrc,
                                                u16* __restrict__ aggb){
  int node = blockIdx.x * 4 + (threadIdx.x >> 6);
  int lane = threadIdx.x & 63;
  int g = lane >> 4, c = lane & 15;
  int beg = row_ptr[node], end = row_ptr[node + 1];
  int T = end - beg;
  int spre = (lane < T) ? esrc[beg + lane] : 0;
  int n64 = T < 64 ? T : 64;
  float acc[8];
  #pragma unroll
  for (int j = 0; j < 8; ++j) acc[j] = 0.f;
  const u16* hc = hb + c * 8;

  int i = 0;
  for (; i + 8 <= n64; i += 8){
    int sA = __shfl(spre, i + g, 64);
    int sB = __shfl(spre, i + 4 + g, 64);
    uint4 vA = *(const uint4*)(hc + (size_t)sA * H_DIM);
    uint4 vB = *(const uint4*)(hc + (size_t)sB * H_DIM);
    float fA[8], fB[8];
    unpk8(vA, fA); unpk8(vB, fB);
    #pragma unroll
    for (int j = 0; j < 8; ++j) acc[j] += fA[j] + fB[j];
  }
  for (; i < n64; i += 4){
    int e = i + g;
    int ce = e < n64 ? e : n64 - 1;
    int s = __shfl(spre, ce, 64);
    uint4 v = *(const uint4*)(hc + (size_t)s * H_DIM);
    float f[8];
    unpk8(v, f);
    float m = (e < n64) ? 1.f : 0.f;
    #pragma unroll
    for (int j = 0; j < 8; ++j) acc[j] += f[j] * m;
  }
  for (int e2 = 64 + g; e2 < T; e2 += 4){   // astronomically rare tail (deg > 64)
    int s = esrc[beg + e2];
    uint4 v = *(const uint4*)(hc + (size_t)s * H_DIM);
    float f[8];
    unpk8(v, f);
    #pragma unroll
    for (int j = 0; j < 8; ++j) acc[j] += f[j];
  }
  #pragma unroll
  for (int j = 0; j < 8; ++j){
    acc[j] += __shfl_xor(acc[j], 16, 64);
    acc[j] += __shfl_xor(acc[j], 32, 64);
  }
  if (g == 0){
    unsigned p[4];
    #pragma unroll
    for (int q = 0; q < 4; ++q)
      p[q] = (unsigned)f2bf(acc[q * 2]) | ((unsigned)f2bf(acc[q * 2 + 1]) << 16);
    uint4 P = make_uint4(p[0], p[1], p[2], p[3]);
    *(uint4*)(aggb + (size_t)node * H_DIM + c * 8) = P;
  }
}

// ======== LDS-staged MFMA GEMMs ========

// ---------- gemm0: fp32 x loaded+converted in-kernel ----------
__global__ __launch_bounds__(512) void k_gemm0(const float* __restrict__ x, const u16* __restrict__ wt,
                                               const float* __restrict__ bias, u16* __restrict__ hbo){
  __shared__ u16 lds[32][128];
  int tid = threadIdx.x;
  int w = tid >> 6, lane = tid & 63;
  int m0 = blockIdx.x * 32;
  {
    int rg = lane >> 4, cb = (lane & 15) << 4;
    int srow = w * 4 + rg;
    int swcb = cb ^ ((srow & 7) << 4);
    const float* xs = x + (size_t)(m0 + srow) * F_IN + (swcb >> 1);
    float4 u = *(const float4*)xs;
    float4 v = *(const float4*)(xs + 4);
    unsigned p0 = (unsigned)f2bf(u.x) | ((unsigned)f2bf(u.y) << 16);
    unsigned p1 = (unsigned)f2bf(u.z) | ((unsigned)f2bf(u.w) << 16);
    unsigned p2 = (unsigned)f2bf(v.x) | ((unsigned)f2bf(v.y) << 16);
    unsigned p3 = (unsigned)f2bf(v.z) | ((unsigned)f2bf(v.w) << 16);
    *(uint4*)((char*)&lds[0][0] + w * 1024 + lane * 16) = make_uint4(p0, p1, p2, p3);
  }
  __syncthreads();

  int arow = lane & 15, kg = lane >> 4;
  int col = w * 16 + arow;
  f32x4 acc[2];
  acc[0] = (f32x4){0.f, 0.f, 0.f, 0.f};
  acc[1] = (f32x4){0.f, 0.f, 0.f, 0.f};
  bf16x8 b[4];
  #pragma unroll
  for (int kk = 0; kk < 4; ++kk)
    b[kk] = *(const bf16x8*)(wt + (size_t)col * F_IN + kk * 32 + kg * 8);
  #pragma unroll
  for (int rt = 0; rt < 2; ++rt){
    int row = rt * 16 + arow;
    const char* base = (const char*)&lds[0][0] + row * 256;
    int sx = (row & 7) << 4;
    #pragma unroll
    for (int kk = 0; kk < 4; ++kk){
      bf16x8 a = *(const bf16x8*)(base + ((kk * 64 + kg * 16) ^ sx));
      acc[rt] = __builtin_amdgcn_mfma_f32_16x16x32_bf16(a, b[kk], acc[rt], 0, 0, 0);
    }
  }
  float bb = bias[col];
  #pragma unroll
  for (int rt = 0; rt < 2; ++rt)
    #pragma unroll
    for (int j = 0; j < 4; ++j){
      int gr = m0 + rt * 16 + kg * 4 + j;
      hbo[(size_t)gr * H_DIM + col] = f2bf(relu_f(acc[rt][j] + bb));
    }
}

__global__ __launch_bounds__(512) void k_rgcn_gemm(const u16* __restrict__ meanb, const u16* __restrict__ hb,
                                                   const u16* __restrict__ wrel, const u16* __restrict__ wroot,
                                                   const float* __restrict__ bias, u16* __restrict__ hbo){
  __shared__ u16 lds[5][32][128];   // 40 KB
  int tid = threadIdx.x;
  int w = tid >> 6, lane = tid & 63;
  int m0 = blockIdx.x * 32;
  int rg = lane >> 4, cb = (lane & 15) << 4;
  int srow = w * 4 + rg;
  int swcb = cb ^ ((srow & 7) << 4);
  #pragma unroll
  for (int s = 0; s < 4; ++s)
    gload16(meanb + ((size_t)(m0 + srow) * R_REL + s) * H_DIM + (swcb >> 1), &lds[s][w * 4][0]);
  gload16(hb + (size_t)(m0 + srow) * H_DIM + (swcb >> 1), &lds[4][w * 4][0]);
  __syncthreads();

  int arow = lane & 15, kg = lane >> 4;
  int col = w * 16 + arow;
  f32x4 acc[2];
  acc[0] = (f32x4){0.f, 0.f, 0.f, 0.f};
  acc[1] = (f32x4){0.f, 0.f, 0.f, 0.f};
  #pragma unroll
  for (int s = 0; s < 5; ++s){
    const u16* WT = (s < 4) ? wrel + (size_t)s * 16384 : wroot;
    bf16x8 b[4];
    #pragma unroll
    for (int kk = 0; kk < 4; ++kk)
      b[kk] = *(const bf16x8*)(WT + (size_t)col * H_DIM + kk * 32 + kg * 8);
    #pragma unroll
    for (int rt = 0; rt < 2; ++rt){
      int row = rt * 16 + arow;
      const char* base = (const char*)&lds[s][0][0] + row * 256;
      int sx = (row & 7) << 4;
      #pragma unroll
      for (int kk = 0; kk < 4; ++kk){
        bf16x8 a = *(const bf16x8*)(base + ((kk * 64 + kg * 16) ^ sx));
        acc[rt] = __builtin_amdgcn_mfma_f32_16x16x32_bf16(a, b[kk], acc[rt], 0, 0, 0);
      }
    }
  }
  float bb = bias[col];
  #pragma unroll
  for (int rt = 0; rt < 2; ++rt)
    #pragma unroll
    for (int j = 0; j < 4; ++j){
      int gr = m0 + rt * 16 + kg * 4 + j;
      hbo[(size_t)gr * H_DIM + col] = f2bf(relu_f(acc[rt][j] + bb));
    }
}

template<int FINAL>
__global__ __launch_bounds__(512) void k_mf_gemm(const u16* __restrict__ aggb, const u16* __restrict__ hb,
                                                 const u16* __restrict__ wl, const u16* __restrict__ wr,
                                                 const float* __restrict__ bl,
                                                 const int* __restrict__ bcount, const int* __restrict__ boff,
                                                 const int* __restrict__ perm,
                                                 u16* __restrict__ hbo, float* __restrict__ hf){
  __shared__ u16 lds[2][32][128];   // 16 KB
  __shared__ int rows_s[32];
  int t = blockIdx.x;
  int d = -1, tile = 0;
  for (int dd = 0; dd <= MAXDEG; ++dd){
    int nt = (bcount[dd] + 31) >> 5;
    if (t < nt){ d = dd; tile = t; break; }
    t -= nt;
  }
  if (d < 0) return;
  int cnt_d = bcount[d];
  int start = boff[d] + tile * 32;
  int nrows = cnt_d - tile * 32; if (nrows > 32) nrows = 32;

  int tid = threadIdx.x;
  int w = tid >> 6, lane = tid & 63;
  if (tid < 32) rows_s[tid] = (tid < nrows) ? perm[start + tid] : -1;

  int rg = lane >> 4, cb = (lane & 15) << 4;
  int srow = w * 4 + rg;
  int swcb = cb ^ ((srow & 7) << 4);
  int node = perm[start + (srow < nrows ? srow : 0)];
  gload16(aggb + (size_t)node * H_DIM + (swcb >> 1), &lds[0][w * 4][0]);
  gload16(hb   + (size_t)node * H_DIM + (swcb >> 1), &lds[1][w * 4][0]);
  __syncthreads();

  int arow = lane & 15, kg = lane >> 4;
  int col = w * 16 + arow;
  f32x4 acc[2];
  acc[0] = (f32x4){0.f, 0.f, 0.f, 0.f};
  acc[1] = (f32x4){0.f, 0.f, 0.f, 0.f};
  #pragma unroll
  for (int s = 0; s < 2; ++s){
    const u16* WT = (s ? wr : wl) + (size_t)d * 16384;
    bf16x8 b[4];
    #pragma unroll
    for (int kk = 0; kk < 4; ++kk)
      b[kk] = *(const bf16x8*)(WT + (size_t)col * H_DIM + kk * 32 + kg * 8);
    #pragma unroll
    for (int rt = 0; rt < 2; ++rt){
      int row = rt * 16 + arow;
      const char* base = (const char*)&lds[s][0][0] + row * 256;
      int sx = (row & 7) << 4;
      #pragma unroll
      for (int kk = 0; kk < 4; ++kk){
        bf16x8 a = *(const bf16x8*)(base + ((kk * 64 + kg * 16) ^ sx));
        acc[rt] = __builtin_amdgcn_mfma_f32_16x16x32_bf16(a, b[kk], acc[rt], 0, 0, 0);
      }
    }
  }
  float bb = bl[(size_t)d * H_DIM + col];
  #pragma unroll
  for (int rt = 0; rt < 2; ++rt)
    #pragma unroll
    for (int j = 0; j < 4; ++j){
      int gr = rows_s[rt * 16 + kg * 4 + j];
      if (gr >= 0){
        float v = acc[rt][j] + bb;
        if (FINAL) hf[(size_t)gr * H_DIM + col] = v;
        else       hbo[(size_t)gr * H_DIM + col] = f2bf(relu_f(v));
      }
    }
}

// ---------- merged pooling + MLP ----------
__global__ __launch_bounds__(256) void k_poolmlp(const float* __restrict__ h, const int* __restrict__ goff,
                                                 const float* __restrict__ W1, const float* __restrict__ b1,
                                                 const float* __restrict__ W2, const float* __restrict__ b2,
                                                 float* __restrict__ out){
  __shared__ float4 sred[8][32];
  __shared__ float pv[128];
  __shared__ float Ts[128];
  int g = blockIdx.x;
  int tid = threadIdx.x;
  int rg = tid >> 5, lane = tid & 31;
  int beg = goff[g], end = goff[g + 1];
  float4 acc = make_float4(0.f, 0.f, 0.f, 0.f);
  for (int n = beg + rg; n < end; n += 8){
    float4 v = ((const float4*)(h + (size_t)n * H_DIM))[lane];
    acc.x += v.x; acc.y += v.y; acc.z += v.z; acc.w += v.w;
  }
  sred[rg][lane] = acc;
  __syncthreads();
  if (tid < 32){
    float4 s = sred[0][tid];
    #pragma unroll
    for (int r = 1; r < 8; ++r){
      float4 v = sred[r][tid];
      s.x += v.x; s.y += v.y; s.z += v.z; s.w += v.w;
    }
    *(float4*)&pv[tid * 4] = s;
  }
  __syncthreads();
  if (tid < 128){
    float s = b1[tid];
    for (int k = 0; k < H_DIM; ++k) s += pv[k] * W1[k * H_DIM + tid];
    Ts[tid] = relu_f(s);
  }
  __syncthreads();
  if (tid < N_OUT){
    float o = b2[tid];
    for (int k = 0; k < H_DIM; ++k) o += Ts[k] * W2[k * N_OUT + tid];
    out[(size_t)g * N_OUT + tid] = o;
  }
}

extern "C" void kernel_launch(void* const* d_in, const int* in_sizes, int n_in,
                              void* d_out, int out_size, void* d_ws, size_t ws_size,
                              hipStream_t stream){
  const float* x      = (const float*)d_in[0];
  const int*   ei     = (const int*)d_in[1];
  const int*   ea     = (const int*)d_in[2];
  const int*   batch  = (const int*)d_in[3];
  const float* W0     = (const float*)d_in[4];
  const float* b0     = (const float*)d_in[5];
  const float* rWrel  = (const float*)d_in[6];
  const float* rWroot = (const float*)d_in[7];
  const float* rb     = (const float*)d_in[8];
  const float* mWl    = (const float*)d_in[9];
  const float* mbl    = (const float*)d_in[10];
  const float* mWr    = (const float*)d_in[11];
  const float* W1     = (const float*)d_in[12];
  const float* b1     = (const float*)d_in[13];
  const float* W2     = (const float*)d_in[14];
  const float* b2     = (const float*)d_in[15];
  float* out = (float*)d_out;

  const int* src = ei;
  const int* dst = ei + N_EDGES;

  char* ws = (char*)d_ws;
  size_t off = 0;
  auto alloc = [&](size_t bytes) -> void* {
    void* p = ws + off;
    off += (bytes + 255) & ~(size_t)255;
    return p;
  };
  u16* hbA     = (u16*)alloc((size_t)N_NODES * H_DIM * 2);
  u16* hbB     = (u16*)alloc((size_t)N_NODES * H_DIM * 2);
  u16* meanb   = (u16*)alloc((size_t)N_NODES * R_REL * H_DIM * 2);
  u16* aggb    = meanb;  // reuse
  float* hf    = (float*)alloc((size_t)N_NODES * H_DIM * 4);
  u16* wt0     = (u16*)alloc((size_t)1 * 16384 * 2);
  u16* wtRel   = (u16*)alloc((size_t)NBLK * R_REL * 16384 * 2);
  u16* wtRoot  = (u16*)alloc((size_t)NBLK * 16384 * 2);
  u16* wtWl    = (u16*)alloc((size_t)NBLK * (MAXDEG + 1) * 16384 * 2);
  u16* wtWr    = (u16*)alloc((size_t)NBLK * (MAXDEG + 1) * 16384 * 2);
  int* cnt4     = (int*)alloc((size_t)N_NODES * R_REL * 4);
  int* deg      = (int*)alloc((size_t)N_NODES * 4);
  int* row_ptr  = (int*)alloc((size_t)(N_NODES + 1) * 4);
  int* rel_off  = (int*)alloc((size_t)N_NODES * R_REL * 4);
  int* cursor   = (int*)alloc((size_t)N_NODES * R_REL * 4);
  int* esrc     = (int*)alloc((size_t)N_EDGES * 4);
  int* bsum     = (int*)alloc((size_t)NSCAN_BLK * 4);
  int* bbase    = (int*)alloc((size_t)NSCAN_BLK * 4);
  int* bhist    = (int*)alloc((size_t)NSCAN_BLK * (MAXDEG + 1) * 4);
  int* pbase    = (int*)alloc((size_t)NSCAN_BLK * (MAXDEG + 1) * 4);
  int* perm     = (int*)alloc((size_t)N_NODES * 4);
  int* bcount   = (int*)alloc(16 * 4);
  int* boff     = (int*)alloc(16 * 4);
  int* goff     = (int*)alloc((size_t)(G_GRAPHS + 1) * 4);

  hipMemsetAsync(cnt4, 0, (size_t)N_NODES * R_REL * 4, stream);

  // graph structure
  k_cnt<<<(N_EDGES + 255) / 256, 256, 0, stream>>>(dst, ea, cnt4);
  k_scan_a<<<NSCAN_BLK, 256, 0, stream>>>(cnt4, deg, row_ptr, bsum, bhist);
  k_scan_bb<<<1, 256, 0, stream>>>(bsum, bbase, bhist, pbase, bcount, boff);
  k_scan_c<<<NSCAN_BLK, 256, 0, stream>>>(row_ptr, bbase, cnt4, rel_off, cursor);
  k_csr_fill<<<(N_EDGES + 255) / 256, 256, 0, stream>>>(src, dst, ea, cursor, esrc);
  k_bfill_goff<<<NSCAN_BLK, 256, 0, stream>>>(deg, pbase, perm, batch, goff);

  // weight conversion
  k_cvtW_all<<<55 * 16, 256, 0, stream>>>(W0, rWrel, rWroot, mWl, mWr,
                                          wt0, wtRel, wtRoot, wtWl, wtWr);

  k_gemm0<<<N_NODES / 32, 512, 0, stream>>>(x, wt0, b0, hbA);

  u16* hin = hbA;
  u16* hout = hbB;
  for (int blk = 0; blk < NBLK; ++blk){
    k_rgcn_agg<<<N_NODES / 4, 256, 0, stream>>>(hin, rel_off, row_ptr, esrc, meanb);
    k_rgcn_gemm<<<N_NODES / 32, 512, 0, stream>>>(meanb, hin,
        wtRel + (size_t)blk * R_REL * 16384,
        wtRoot + (size_t)blk * 16384,
        rb + (size_t)blk * H_DIM, hout);
    { u16* tmp = hin; hin = hout; hout = tmp; }

    k_mf_agg<<<N_NODES / 4, 256, 0, stream>>>(hin, row_ptr, esrc, aggb);
    const u16* wl_b = wtWl + (size_t)blk * (MAXDEG + 1) * 16384;
    const u16* wr_b = wtWr + (size_t)blk * (MAXDEG + 1) * 16384;
    const float* bl_b = mbl + (size_t)blk * (MAXDEG + 1) * H_DIM;
    int grid_mf = N_NODES / 32 + MAXDEG + 1;
    if (blk == NBLK - 1)
      k_mf_gemm<1><<<grid_mf, 512, 0, stream>>>(aggb, hin, wl_b, wr_b, bl_b,
                                                bcount, boff, perm, hout, hf);
    else
      k_mf_gemm<0><<<grid_mf, 512, 0, stream>>>(aggb, hin, wl_b, wr_b, bl_b,
                                                bcount, boff, perm, hout, hf);
    { u16* tmp = hin; hin = hout; hout = tmp; }
  }

  k_poolmlp<<<G_GRAPHS, 256, 0, stream>>>(hf, goff, W1, b1, W2, b2, out);
}